// Round 18
// baseline (511.852 us; speedup 1.0000x reference)
//
#include <hip/hip_runtime.h>

#define NN 100000
#define NE 3200000
#define DD 128
#define KC 10
#define NITER 10
#define NBK 1024            // k_iter blocks: 128 per XCD x 8 XCDs
#define NPAIR (NN / 2)
#define NB4 (NPAIR / 4)     // 12500 batches of 4 pairs
#define NE4 (NE / 4)
#define NWX 512             // waves per XCD partition
#define NR2 128             // p2 rows (= NBK/8)

template <int CTRL, int RM>
__device__ __forceinline__ float dppadd(float v) {
  int t = __builtin_amdgcn_update_dpp(0, __builtin_bit_cast(int, v), CTRL, RM,
                                      0xF, true);
  return v + __builtin_bit_cast(float, t);
}

// After this: lane 31 holds sum of lanes 0..31, lane 63 holds sum of 32..63.
__device__ __forceinline__ float halfsum_tail(float v) {
  v = dppadd<0x111, 0xF>(v);  // row_shr:1
  v = dppadd<0x112, 0xF>(v);  // row_shr:2
  v = dppadd<0x114, 0xF>(v);  // row_shr:4
  v = dppadd<0x118, 0xF>(v);  // row_shr:8
  v = dppadd<0x142, 0xA>(v);  // row_bcast:15 into rows 1,3
  return v;
}
// broadcast lane 31 -> lanes 0..31 and lane 63 -> lanes 32..63
__device__ __forceinline__ int bcast31i(int v) {
  return __builtin_amdgcn_ds_swizzle(v, 0x3E0);
}

// ---- fused assign+accumulate, half-wave per row, XCD-affine batches ----
__global__ __launch_bounds__(256, 2) void k_iter6(
    const float* __restrict__ x, const float* __restrict__ csrc,
    float* __restrict__ partial, float* __restrict__ cntpart,
    unsigned char* __restrict__ cl8, int last) {
  __shared__ float cs[KC][DD];
  __shared__ float wsum[4][KC][DD];
  __shared__ float wcnt[4][KC];
  const int tid = threadIdx.x;
  float* wsf = (float*)wsum;
  for (int i = tid; i < KC * DD; i += 256) ((float*)cs)[i] = csrc[i];
  for (int i = tid; i < 4 * KC * DD; i += 256) wsf[i] = 0.f;
  __syncthreads();
  const int w = tid >> 6, lane = tid & 63, half = lane >> 5, hl = lane & 31;

  float4 cfrag[KC];
  float bias[KC];
#pragma unroll
  for (int j = 0; j < KC; ++j) {
    const float4 c4 = *(const float4*)&cs[j][hl * 4];
    cfrag[j] = c4;
    bias[j] = -0.5f * (c4.x * c4.x + c4.y * c4.y + c4.z * c4.z + c4.w * c4.w);
  }
  unsigned int cntlo = 0, cnthi = 0;  // 5 x 6-bit counters each

  float* const wrow = &wsum[w][0][hl * 4];
  const float4* __restrict__ x4 = (const float4*)x;

  const int xcd = blockIdx.x & 7;
  const int wk = (blockIdx.x >> 3) * 4 + w;  // wave within XCD, 0..511
  const int bs = (xcd * NB4) / 8;
  const int be = ((xcd + 1) * NB4) / 8;

  float4 vA[4], vB[4];

  auto compute = [&](const float4* v, int B) {
#pragma unroll
    for (int u = 0; u < 4; ++u) {
      const int row = 8 * B + 2 * u + half;
      float d[KC];
#pragma unroll
      for (int j = 0; j < KC; ++j)
        d[j] = bias[j] + v[u].x * cfrag[j].x + v[u].y * cfrag[j].y +
               v[u].z * cfrag[j].z + v[u].w * cfrag[j].w;
#pragma unroll
      for (int j = 0; j < KC; ++j) d[j] = halfsum_tail(d[j]);
      int best = 0;  // meaningful in lanes 31/63 only
      float bd = d[0];
#pragma unroll
      for (int j = 1; j < KC; ++j) {
        if (d[j] > bd) { bd = d[j]; best = j; }
      }
      const int bown = bcast31i(best);
      const int bother = __shfl_xor(bown, 32);
      const unsigned sh = 6u * (unsigned)bown;
      cntlo += (bown < 5) ? (1u << sh) : 0u;
      cnthi += (bown >= 5) ? (1u << (sh - 30u)) : 0u;
      if (last && hl == 0) cl8[row] = (unsigned char)bown;

      if (bown == bother) {  // wave-uniform: both rows -> same centroid
        float4 vs;
        vs.x = v[u].x + __shfl_xor(v[u].x, 32);
        vs.y = v[u].y + __shfl_xor(v[u].y, 32);
        vs.z = v[u].z + __shfl_xor(v[u].z, 32);
        vs.w = v[u].w + __shfl_xor(v[u].w, 32);
        if (half == 0) {
          float4 t = *(float4*)&wrow[bown * DD];
          t.x += vs.x; t.y += vs.y; t.z += vs.z; t.w += vs.w;
          *(float4*)&wrow[bown * DD] = t;
        }
      } else {  // disjoint LDS addresses
        float4 t = *(float4*)&wrow[bown * DD];
        t.x += v[u].x; t.y += v[u].y; t.z += v[u].z; t.w += v[u].w;
        *(float4*)&wrow[bown * DD] = t;
      }
    }
  };
  auto loadb = [&](float4* v, int B) {
    const size_t rb = (size_t)(8 * B) * 32;
#pragma unroll
    for (int u = 0; u < 4; ++u) v[u] = x4[rb + (size_t)(2 * u + half) * 32 + hl];
  };

  int B = bs + wk;
  if (B < be) {
    loadb(vA, B);
    for (;;) {
      if (B + NWX < be) loadb(vB, B + NWX);
      compute(vA, B);
      B += NWX;
      if (B >= be) break;
      if (B + NWX < be) loadb(vA, B + NWX);
      compute(vB, B);
      B += NWX;
      if (B >= be) break;
    }
  }
  // flush
  __syncthreads();
  for (int i = tid; i < KC * DD; i += 256)
    partial[(size_t)blockIdx.x * (KC * DD) + i] =
        wsf[i] + wsf[KC * DD + i] + wsf[2 * KC * DD + i] + wsf[3 * KC * DD + i];
  cntlo += __shfl_xor(cntlo, 32);
  cnthi += __shfl_xor(cnthi, 32);
  if (lane == 0) {
#pragma unroll
    for (int j = 0; j < 5; ++j) {
      wcnt[w][j] = (float)((cntlo >> (6 * j)) & 63u);
      wcnt[w][j + 5] = (float)((cnthi >> (6 * j)) & 63u);
    }
  }
  __syncthreads();
  if (tid < KC)
    cntpart[blockIdx.x * KC + tid] =
        wcnt[0][tid] + wcnt[1][tid] + wcnt[2][tid] + wcnt[3][tid];
}

// ---- level-1 reduce: 128 blocks, each sums 8 contiguous partial rows ----
__global__ __launch_bounds__(256) void k_red1(const float* __restrict__ partial,
                                              float* __restrict__ p2) {
  const int b = blockIdx.x;  // <<<NR2, 256>>>
  const size_t base = (size_t)b * 8 * (KC * DD);
  for (int i = threadIdx.x; i < KC * DD; i += 256) {
    float s = 0.f;
#pragma unroll
    for (int m = 0; m < 8; ++m) s += partial[base + (size_t)m * (KC * DD) + i];
    p2[(size_t)b * (KC * DD) + i] = s;
  }
}

// ---- centroid update from p2 (128 rows): 160 blocks, coalesced 8-col ----
__global__ __launch_bounds__(256) void k_update2(
    const float* __restrict__ p2, const float* __restrict__ cntpart,
    float* __restrict__ c) {
  const int j = blockIdx.x >> 4, q = blockIdx.x & 15;  // <<<KC*16, 256>>>
  const int tid = threadIdx.x;
  __shared__ float creds[256];
  __shared__ float red2[32][8];
  float cf = 0.f;
#pragma unroll
  for (int m = 0; m < NBK / 256; ++m) cf += cntpart[(tid + 256 * m) * KC + j];
  creds[tid] = cf;
  __syncthreads();
  for (int s = 128; s > 0; s >>= 1) {
    if (tid < s) creds[tid] += creds[tid + s];
    __syncthreads();
  }
  const float denom = fmaxf(creds[0], 1.f);
  const int cc = tid & 7, r = tid >> 3;  // 8 cols x 32 row-slices
  const int col = j * DD + q * 8 + cc;
  float s0 = 0.f;
#pragma unroll
  for (int m = 0; m < NR2 / 32; ++m)
    s0 += p2[(size_t)(r + 32 * m) * (KC * DD) + col];
  red2[r][cc] = s0;
  __syncthreads();
  if (tid < 8) {
    float t = 0.f;
#pragma unroll
    for (int rr = 0; rr < 32; ++rr) t += red2[rr][tid];
    c[j * DD + q * 8 + tid] = t / denom;
  }
}

// ------------- q/v projection: block = (mat, row i), 128 threads ------------
__global__ __launch_bounds__(DD) void k_qv(const float* __restrict__ c,
                                           const float* __restrict__ WQ,
                                           const float* __restrict__ WV,
                                           float* __restrict__ qv) {
  const int b = blockIdx.x;  // <<<2*KC, DD>>>
  const int mat = b / KC, i = b % KC;
  const float* __restrict__ W = mat ? WV : WQ;
  __shared__ float cr[DD];
  const int k = threadIdx.x;
  cr[k] = c[i * DD + k];
  __syncthreads();
  float a = 0.f;
#pragma unroll 8
  for (int m = 0; m < DD; ++m) a += cr[m] * W[m * DD + k];
  qv[(size_t)mat * KC * DD + i * DD + k] = a;
}

// ------------- 10x10 scores + row softmax -------------
__global__ __launch_bounds__(DD) void k_att(const float* __restrict__ qv,
                                            float* __restrict__ CA) {
  __shared__ float q[KC][DD + 2], v[KC][DD + 2], pr[KC][KC];
  const int tid = threadIdx.x;  // <<<1, DD>>>
  for (int i = 0; i < KC; ++i) {
    q[i][tid] = qv[i * DD + tid];
    v[i][tid] = qv[KC * DD + i * DD + tid];
  }
  __syncthreads();
  if (tid < KC * KC) {
    const int i = tid / KC, l = tid % KC;
    float acc = 0.f;
#pragma unroll 8
    for (int m = 0; m < DD; ++m) acc += q[i][m] * v[l][m];
    pr[i][l] = acc / sqrtf((float)DD);
  }
  __syncthreads();
  if (tid < KC) {
    float mx = pr[tid][0];
    for (int l = 1; l < KC; ++l) mx = fmaxf(mx, pr[tid][l]);
    float e[KC];
    float s = 0.f;
    for (int l = 0; l < KC; ++l) {
      e[l] = expf(pr[tid][l] - mx);
      s += e[l];
    }
    for (int l = 0; l < KC; ++l) CA[tid * KC + l] = e[l] / s;
  }
}

// ------------- edge histogram (8 dispatches) --------
__global__ __launch_bounds__(256) void k_cnt(const int* __restrict__ e0,
                                             const int* __restrict__ e1,
                                             const unsigned char* __restrict__ cl8,
                                             int* __restrict__ cnt, int base) {
  const int i = base + blockIdx.x * 256 + threadIdx.x;  // int4 index
  if (i >= NE4) return;
  const int4 a = ((const int4*)e0)[i];
  const int4 b = ((const int4*)e1)[i];
  atomicAdd(&cnt[(size_t)a.x * KC + cl8[b.x]], 1);
  atomicAdd(&cnt[(size_t)a.y * KC + cl8[b.y]], 1);
  atomicAdd(&cnt[(size_t)a.z * KC + cl8[b.z]], 1);
  atomicAdd(&cnt[(size_t)a.w * KC + cl8[b.w]], 1);
}

// --------- per-node {denominator, cluster} packed as float2 ---------
__global__ __launch_bounds__(256) void k_tab2(
    const unsigned char* __restrict__ cl8, const int* __restrict__ cnt,
    const float* __restrict__ CA, float2* __restrict__ den2) {
  __shared__ float cas[KC * KC];
  __shared__ float rm[KC];
  if (threadIdx.x < KC * KC) cas[threadIdx.x] = CA[threadIdx.x];
  __syncthreads();
  if (threadIdx.x < KC) {
    float m = cas[threadIdx.x * KC];
    for (int l = 1; l < KC; ++l) m = fmaxf(m, cas[threadIdx.x * KC + l]);
    rm[threadIdx.x] = m;
  }
  __syncthreads();
  const int n = blockIdx.x * 256 + threadIdx.x;
  if (n >= NN) return;
  const int s = cl8[n];
  const float m = rm[s];
  const int2* __restrict__ cr = (const int2*)(cnt + (size_t)n * KC);
  float dsum = 0.f;
#pragma unroll
  for (int h = 0; h < 5; ++h) {
    const int2 cj = cr[h];
    dsum += (float)cj.x * expf(cas[s * KC + 2 * h] - m);
    dsum += (float)cj.y * expf(cas[s * KC + 2 * h + 1] - m);
  }
  den2[n] = float2{dsum, (float)s};
}

// ---- gather (8 edges/thread): out[e] = exp(ca[s][cb]-rm[s]) / (den+eps) ----
__global__ __launch_bounds__(256) void k_gather2(
    const int* __restrict__ e0, const int* __restrict__ e1,
    const unsigned char* __restrict__ cl8, const float* __restrict__ CA,
    const float2* __restrict__ den2, float* __restrict__ out) {
  __shared__ float cas[KC * KC];
  __shared__ float rm[KC];
  if (threadIdx.x < KC * KC) cas[threadIdx.x] = CA[threadIdx.x];
  __syncthreads();
  if (threadIdx.x < KC) {
    float m = cas[threadIdx.x * KC];
    for (int l = 1; l < KC; ++l) m = fmaxf(m, cas[threadIdx.x * KC + l]);
    rm[threadIdx.x] = m;
  }
  __syncthreads();
  const int t = blockIdx.x * 256 + threadIdx.x;
  const int i0 = t * 2;  // two int4 groups = 8 edges
  if (i0 >= NE4) return;
  const int4 a0 = ((const int4*)e0)[i0];
  const int4 b0 = ((const int4*)e1)[i0];
  const bool two = (i0 + 1 < NE4);
  int4 a1 = a0, b1 = b0;
  if (two) {
    a1 = ((const int4*)e0)[i0 + 1];
    b1 = ((const int4*)e1)[i0 + 1];
  }
  // batch all gathers (8 den2 + 8 cl8 in flight)
  const float2 d0 = den2[a0.x], d1 = den2[a0.y], d2 = den2[a0.z],
               d3 = den2[a0.w], d4 = den2[a1.x], d5 = den2[a1.y],
               d6 = den2[a1.z], d7 = den2[a1.w];
  const int c0 = cl8[b0.x], c1 = cl8[b0.y], c2 = cl8[b0.z], c3 = cl8[b0.w],
            c4 = cl8[b1.x], c5 = cl8[b1.y], c6 = cl8[b1.z], c7 = cl8[b1.w];
  float4 r0, r1;
  {
    const int s = (int)d0.y;
    r0.x = expf(cas[s * KC + c0] - rm[s]) / (d0.x + 1e-16f);
  }
  {
    const int s = (int)d1.y;
    r0.y = expf(cas[s * KC + c1] - rm[s]) / (d1.x + 1e-16f);
  }
  {
    const int s = (int)d2.y;
    r0.z = expf(cas[s * KC + c2] - rm[s]) / (d2.x + 1e-16f);
  }
  {
    const int s = (int)d3.y;
    r0.w = expf(cas[s * KC + c3] - rm[s]) / (d3.x + 1e-16f);
  }
  ((float4*)out)[i0] = r0;
  if (two) {
    {
      const int s = (int)d4.y;
      r1.x = expf(cas[s * KC + c4] - rm[s]) / (d4.x + 1e-16f);
    }
    {
      const int s = (int)d5.y;
      r1.y = expf(cas[s * KC + c5] - rm[s]) / (d5.x + 1e-16f);
    }
    {
      const int s = (int)d6.y;
      r1.z = expf(cas[s * KC + c6] - rm[s]) / (d6.x + 1e-16f);
    }
    {
      const int s = (int)d7.y;
      r1.w = expf(cas[s * KC + c7] - rm[s]) / (d7.x + 1e-16f);
    }
    ((float4*)out)[i0 + 1] = r1;
  }
}

// ---------------- launch ----------------
extern "C" void kernel_launch(void* const* d_in, const int* in_sizes, int n_in,
                              void* d_out, int out_size, void* d_ws,
                              size_t ws_size, hipStream_t stream) {
  const float* x = (const float*)d_in[0];
  const int* edge = (const int*)d_in[1];
  const float* WQ = (const float*)d_in[2];
  const float* WV = (const float*)d_in[3];
  float* out = (float*)d_out;
  const int* e0 = edge;
  const int* e1 = edge + NE;

  float* ws = (float*)d_ws;
  float* c = ws;                                     // 1280
  float* CA = ws + 1280;                             // 112 (pad)
  float* qv = ws + 1392;                             // 2560
  float2* den2 = (float2*)(qv + 2 * KC * DD);        // NN float2
  float* partial = (float*)(den2 + NN);              // NBK*KC*DD
  float* p2 = partial + (size_t)NBK * KC * DD;       // NR2*KC*DD
  float* cntpart = p2 + (size_t)NR2 * KC * DD;       // NBK*KC
  int* cnt = (int*)(cntpart + NBK * KC);             // NN*KC ints
  unsigned char* cl8 = (unsigned char*)(cnt + (size_t)NN * KC);  // NN bytes
  // total ~11 MB

  hipMemsetAsync(cnt, 0, (size_t)NN * KC * sizeof(int), stream);

  for (int it = 0; it < NITER; ++it) {
    const float* csrc = (it == 0) ? x : c;
    k_iter6<<<NBK, 256, 0, stream>>>(x, csrc, partial, cntpart, cl8,
                                     it == NITER - 1);
    k_red1<<<NR2, 256, 0, stream>>>(partial, p2);
    k_update2<<<KC * 16, 256, 0, stream>>>(p2, cntpart, c);
  }
  k_qv<<<2 * KC, DD, 0, stream>>>(c, WQ, WV, qv);
  k_att<<<1, DD, 0, stream>>>(qv, CA);
  const int TOT_BLKS = (NE4 + 255) / 256;   // 3125
  const int QB8 = (TOT_BLKS + 7) / 8;       // 391
  for (int q = 0; q < 8; ++q) {
    const int nb = (q < 7) ? QB8 : (TOT_BLKS - 7 * QB8);
    k_cnt<<<nb, 256, 0, stream>>>(e0, e1, cl8, cnt, q * QB8 * 256);
  }
  k_tab2<<<(NN + 255) / 256, 256, 0, stream>>>(cl8, cnt, CA, den2);
  const int GB = (NE4 / 2 + 255) / 256;  // 1563
  k_gather2<<<GB, 256, 0, stream>>>(e0, e1, cl8, CA, den2, out);
}

// Round 19
// 489.365 us; speedup vs baseline: 1.0460x; 1.0460x over previous
//
#include <hip/hip_runtime.h>

#define NN 100000
#define NE 3200000
#define DD 128
#define KC 10
#define NITER 10
#define NBK 1024            // k_iter blocks: 128 per XCD x 8 XCDs
#define NPAIR (NN / 2)
#define NB4 (NPAIR / 4)     // 12500 batches of 4 pairs
#define NE4 (NE / 4)
#define NWX 512             // waves per XCD partition

template <int CTRL, int RM>
__device__ __forceinline__ float dppadd(float v) {
  int t = __builtin_amdgcn_update_dpp(0, __builtin_bit_cast(int, v), CTRL, RM,
                                      0xF, true);
  return v + __builtin_bit_cast(float, t);
}

// After this: lane 31 holds sum of lanes 0..31, lane 63 holds sum of 32..63.
__device__ __forceinline__ float halfsum_tail(float v) {
  v = dppadd<0x111, 0xF>(v);  // row_shr:1
  v = dppadd<0x112, 0xF>(v);  // row_shr:2
  v = dppadd<0x114, 0xF>(v);  // row_shr:4
  v = dppadd<0x118, 0xF>(v);  // row_shr:8
  v = dppadd<0x142, 0xA>(v);  // row_bcast:15 into rows 1,3
  return v;
}
// broadcast lane 31 -> lanes 0..31 and lane 63 -> lanes 32..63
__device__ __forceinline__ int bcast31i(int v) {
  return __builtin_amdgcn_ds_swizzle(v, 0x3E0);
}

// ---- fused assign+accumulate, half-wave per row, XCD-affine batches ----
__global__ __launch_bounds__(256, 2) void k_iter6(
    const float* __restrict__ x, const float* __restrict__ csrc,
    float* __restrict__ partial, float* __restrict__ cntpart,
    unsigned char* __restrict__ cl8, int last) {
  __shared__ float cs[KC][DD];
  __shared__ float wsum[4][KC][DD];
  __shared__ float wcnt[4][KC];
  const int tid = threadIdx.x;
  float* wsf = (float*)wsum;
  for (int i = tid; i < KC * DD; i += 256) ((float*)cs)[i] = csrc[i];
  for (int i = tid; i < 4 * KC * DD; i += 256) wsf[i] = 0.f;
  __syncthreads();
  const int w = tid >> 6, lane = tid & 63, half = lane >> 5, hl = lane & 31;

  float4 cfrag[KC];
  float bias[KC];
#pragma unroll
  for (int j = 0; j < KC; ++j) {
    const float4 c4 = *(const float4*)&cs[j][hl * 4];
    cfrag[j] = c4;
    bias[j] = -0.5f * (c4.x * c4.x + c4.y * c4.y + c4.z * c4.z + c4.w * c4.w);
  }
  unsigned int cntlo = 0, cnthi = 0;  // 5 x 6-bit counters each

  float* const wrow = &wsum[w][0][hl * 4];
  const float4* __restrict__ x4 = (const float4*)x;

  const int xcd = blockIdx.x & 7;
  const int wk = (blockIdx.x >> 3) * 4 + w;  // wave within XCD, 0..511
  const int bs = (xcd * NB4) / 8;
  const int be = ((xcd + 1) * NB4) / 8;

  float4 vA[4], vB[4];

  auto compute = [&](const float4* v, int B) {
#pragma unroll
    for (int u = 0; u < 4; ++u) {
      const int row = 8 * B + 2 * u + half;
      float d[KC];
#pragma unroll
      for (int j = 0; j < KC; ++j)
        d[j] = bias[j] + v[u].x * cfrag[j].x + v[u].y * cfrag[j].y +
               v[u].z * cfrag[j].z + v[u].w * cfrag[j].w;
#pragma unroll
      for (int j = 0; j < KC; ++j) d[j] = halfsum_tail(d[j]);
      int best = 0;  // meaningful in lanes 31/63 only
      float bd = d[0];
#pragma unroll
      for (int j = 1; j < KC; ++j) {
        if (d[j] > bd) { bd = d[j]; best = j; }
      }
      const int bown = bcast31i(best);
      const int bother = __shfl_xor(bown, 32);
      const unsigned sh = 6u * (unsigned)bown;
      cntlo += (bown < 5) ? (1u << sh) : 0u;
      cnthi += (bown >= 5) ? (1u << (sh - 30u)) : 0u;
      if (last && hl == 0) cl8[row] = (unsigned char)bown;

      if (bown == bother) {  // wave-uniform: both rows -> same centroid
        float4 vs;
        vs.x = v[u].x + __shfl_xor(v[u].x, 32);
        vs.y = v[u].y + __shfl_xor(v[u].y, 32);
        vs.z = v[u].z + __shfl_xor(v[u].z, 32);
        vs.w = v[u].w + __shfl_xor(v[u].w, 32);
        if (half == 0) {
          float4 t = *(float4*)&wrow[bown * DD];
          t.x += vs.x; t.y += vs.y; t.z += vs.z; t.w += vs.w;
          *(float4*)&wrow[bown * DD] = t;
        }
      } else {  // disjoint LDS addresses
        float4 t = *(float4*)&wrow[bown * DD];
        t.x += v[u].x; t.y += v[u].y; t.z += v[u].z; t.w += v[u].w;
        *(float4*)&wrow[bown * DD] = t;
      }
    }
  };
  auto loadb = [&](float4* v, int B) {
    const size_t rb = (size_t)(8 * B) * 32;
#pragma unroll
    for (int u = 0; u < 4; ++u) v[u] = x4[rb + (size_t)(2 * u + half) * 32 + hl];
  };

  int B = bs + wk;
  if (B < be) {
    loadb(vA, B);
    for (;;) {
      if (B + NWX < be) loadb(vB, B + NWX);
      compute(vA, B);
      B += NWX;
      if (B >= be) break;
      if (B + NWX < be) loadb(vA, B + NWX);
      compute(vB, B);
      B += NWX;
      if (B >= be) break;
    }
  }
  // flush
  __syncthreads();
  for (int i = tid; i < KC * DD; i += 256)
    partial[(size_t)blockIdx.x * (KC * DD) + i] =
        wsf[i] + wsf[KC * DD + i] + wsf[2 * KC * DD + i] + wsf[3 * KC * DD + i];
  cntlo += __shfl_xor(cntlo, 32);
  cnthi += __shfl_xor(cnthi, 32);
  if (lane == 0) {
#pragma unroll
    for (int j = 0; j < 5; ++j) {
      wcnt[w][j] = (float)((cntlo >> (6 * j)) & 63u);
      wcnt[w][j + 5] = (float)((cnthi >> (6 * j)) & 63u);
    }
  }
  __syncthreads();
  if (tid < KC)
    cntpart[blockIdx.x * KC + tid] =
        wcnt[0][tid] + wcnt[1][tid] + wcnt[2][tid] + wcnt[3][tid];
}

// ------ centroid update: 160 blocks, block=(j, 8-col group), coalesced ------
__global__ __launch_bounds__(256) void k_update2(
    const float* __restrict__ partial, const float* __restrict__ cntpart,
    float* __restrict__ c) {
  const int j = blockIdx.x >> 4, q = blockIdx.x & 15;  // <<<KC*16, 256>>>
  const int tid = threadIdx.x;
  __shared__ float creds[256];
  __shared__ float red2[32][8];
  float cf = 0.f;
#pragma unroll
  for (int m = 0; m < NBK / 256; ++m) cf += cntpart[(tid + 256 * m) * KC + j];
  creds[tid] = cf;
  __syncthreads();
  for (int s = 128; s > 0; s >>= 1) {
    if (tid < s) creds[tid] += creds[tid + s];
    __syncthreads();
  }
  const float denom = fmaxf(creds[0], 1.f);
  const int cc = tid & 7, r = tid >> 3;  // 8 cols x 32 row-slices
  const int col = j * DD + q * 8 + cc;
  float s0 = 0.f;
#pragma unroll 8
  for (int m = 0; m < NBK / 32; ++m)
    s0 += partial[(size_t)(r + 32 * m) * (KC * DD) + col];
  red2[r][cc] = s0;
  __syncthreads();
  if (tid < 8) {
    float t = 0.f;
#pragma unroll
    for (int rr = 0; rr < 32; ++rr) t += red2[rr][tid];
    c[j * DD + q * 8 + tid] = t / denom;
  }
}

// ------------- q/v projection: block = (mat, row i), 128 threads ------------
__global__ __launch_bounds__(DD) void k_qv(const float* __restrict__ c,
                                           const float* __restrict__ WQ,
                                           const float* __restrict__ WV,
                                           float* __restrict__ qv) {
  const int b = blockIdx.x;  // <<<2*KC, DD>>>
  const int mat = b / KC, i = b % KC;
  const float* __restrict__ W = mat ? WV : WQ;
  __shared__ float cr[DD];
  const int k = threadIdx.x;
  cr[k] = c[i * DD + k];
  __syncthreads();
  float a = 0.f;
#pragma unroll 8
  for (int m = 0; m < DD; ++m) a += cr[m] * W[m * DD + k];
  qv[(size_t)mat * KC * DD + i * DD + k] = a;
}

// ------------- 10x10 scores + row softmax -------------
__global__ __launch_bounds__(DD) void k_att(const float* __restrict__ qv,
                                            float* __restrict__ CA) {
  __shared__ float q[KC][DD + 2], v[KC][DD + 2], pr[KC][KC];
  const int tid = threadIdx.x;  // <<<1, DD>>>
  for (int i = 0; i < KC; ++i) {
    q[i][tid] = qv[i * DD + tid];
    v[i][tid] = qv[KC * DD + i * DD + tid];
  }
  __syncthreads();
  if (tid < KC * KC) {
    const int i = tid / KC, l = tid % KC;
    float acc = 0.f;
#pragma unroll 8
    for (int m = 0; m < DD; ++m) acc += q[i][m] * v[l][m];
    pr[i][l] = acc / sqrtf((float)DD);
  }
  __syncthreads();
  if (tid < KC) {
    float mx = pr[tid][0];
    for (int l = 1; l < KC; ++l) mx = fmaxf(mx, pr[tid][l]);
    float e[KC];
    float s = 0.f;
    for (int l = 0; l < KC; ++l) {
      e[l] = expf(pr[tid][l] - mx);
      s += e[l];
    }
    for (int l = 0; l < KC; ++l) CA[tid * KC + l] = e[l] / s;
  }
}

// ------------- edge histogram (2 dispatches) --------
__global__ __launch_bounds__(256) void k_cnt(const int* __restrict__ e0,
                                             const int* __restrict__ e1,
                                             const unsigned char* __restrict__ cl8,
                                             int* __restrict__ cnt, int base) {
  const int i = base + blockIdx.x * 256 + threadIdx.x;  // int4 index
  if (i >= NE4) return;
  const int4 a = ((const int4*)e0)[i];
  const int4 b = ((const int4*)e1)[i];
  atomicAdd(&cnt[(size_t)a.x * KC + cl8[b.x]], 1);
  atomicAdd(&cnt[(size_t)a.y * KC + cl8[b.y]], 1);
  atomicAdd(&cnt[(size_t)a.z * KC + cl8[b.z]], 1);
  atomicAdd(&cnt[(size_t)a.w * KC + cl8[b.w]], 1);
}

// --------- per-node {denominator, cluster} packed as float2 ---------
__global__ __launch_bounds__(256) void k_tab2(
    const unsigned char* __restrict__ cl8, const int* __restrict__ cnt,
    const float* __restrict__ CA, float2* __restrict__ den2) {
  __shared__ float cas[KC * KC];
  __shared__ float rm[KC];
  if (threadIdx.x < KC * KC) cas[threadIdx.x] = CA[threadIdx.x];
  __syncthreads();
  if (threadIdx.x < KC) {
    float m = cas[threadIdx.x * KC];
    for (int l = 1; l < KC; ++l) m = fmaxf(m, cas[threadIdx.x * KC + l]);
    rm[threadIdx.x] = m;
  }
  __syncthreads();
  const int n = blockIdx.x * 256 + threadIdx.x;
  if (n >= NN) return;
  const int s = cl8[n];
  const float m = rm[s];
  const int2* __restrict__ cr = (const int2*)(cnt + (size_t)n * KC);
  float dsum = 0.f;
#pragma unroll
  for (int h = 0; h < 5; ++h) {
    const int2 cj = cr[h];
    dsum += (float)cj.x * expf(cas[s * KC + 2 * h] - m);
    dsum += (float)cj.y * expf(cas[s * KC + 2 * h + 1] - m);
  }
  den2[n] = float2{dsum, (float)s};
}

// ---- gather (8 edges/thread): out[e] = exp(ca[s][cb]-rm[s]) / (den+eps) ----
__global__ __launch_bounds__(256) void k_gather2(
    const int* __restrict__ e0, const int* __restrict__ e1,
    const unsigned char* __restrict__ cl8, const float* __restrict__ CA,
    const float2* __restrict__ den2, float* __restrict__ out) {
  __shared__ float cas[KC * KC];
  __shared__ float rm[KC];
  if (threadIdx.x < KC * KC) cas[threadIdx.x] = CA[threadIdx.x];
  __syncthreads();
  if (threadIdx.x < KC) {
    float m = cas[threadIdx.x * KC];
    for (int l = 1; l < KC; ++l) m = fmaxf(m, cas[threadIdx.x * KC + l]);
    rm[threadIdx.x] = m;
  }
  __syncthreads();
  const int t = blockIdx.x * 256 + threadIdx.x;
  const int i0 = t * 2;  // two int4 groups = 8 edges
  if (i0 >= NE4) return;
  const int4 a0 = ((const int4*)e0)[i0];
  const int4 b0 = ((const int4*)e1)[i0];
  const bool two = (i0 + 1 < NE4);
  int4 a1 = a0, b1 = b0;
  if (two) {
    a1 = ((const int4*)e0)[i0 + 1];
    b1 = ((const int4*)e1)[i0 + 1];
  }
  const float2 d0 = den2[a0.x], d1 = den2[a0.y], d2 = den2[a0.z],
               d3 = den2[a0.w], d4 = den2[a1.x], d5 = den2[a1.y],
               d6 = den2[a1.z], d7 = den2[a1.w];
  const int c0 = cl8[b0.x], c1 = cl8[b0.y], c2 = cl8[b0.z], c3 = cl8[b0.w],
            c4 = cl8[b1.x], c5 = cl8[b1.y], c6 = cl8[b1.z], c7 = cl8[b1.w];
  float4 r0, r1;
  {
    const int s = (int)d0.y;
    r0.x = expf(cas[s * KC + c0] - rm[s]) / (d0.x + 1e-16f);
  }
  {
    const int s = (int)d1.y;
    r0.y = expf(cas[s * KC + c1] - rm[s]) / (d1.x + 1e-16f);
  }
  {
    const int s = (int)d2.y;
    r0.z = expf(cas[s * KC + c2] - rm[s]) / (d2.x + 1e-16f);
  }
  {
    const int s = (int)d3.y;
    r0.w = expf(cas[s * KC + c3] - rm[s]) / (d3.x + 1e-16f);
  }
  ((float4*)out)[i0] = r0;
  if (two) {
    {
      const int s = (int)d4.y;
      r1.x = expf(cas[s * KC + c4] - rm[s]) / (d4.x + 1e-16f);
    }
    {
      const int s = (int)d5.y;
      r1.y = expf(cas[s * KC + c5] - rm[s]) / (d5.x + 1e-16f);
    }
    {
      const int s = (int)d6.y;
      r1.z = expf(cas[s * KC + c6] - rm[s]) / (d6.x + 1e-16f);
    }
    {
      const int s = (int)d7.y;
      r1.w = expf(cas[s * KC + c7] - rm[s]) / (d7.x + 1e-16f);
    }
    ((float4*)out)[i0 + 1] = r1;
  }
}

// ---------------- launch ----------------
extern "C" void kernel_launch(void* const* d_in, const int* in_sizes, int n_in,
                              void* d_out, int out_size, void* d_ws,
                              size_t ws_size, hipStream_t stream) {
  const float* x = (const float*)d_in[0];
  const int* edge = (const int*)d_in[1];
  const float* WQ = (const float*)d_in[2];
  const float* WV = (const float*)d_in[3];
  float* out = (float*)d_out;
  const int* e0 = edge;
  const int* e1 = edge + NE;

  float* ws = (float*)d_ws;
  float* c = ws;                                     // 1280
  float* CA = ws + 1280;                             // 112 (pad)
  float* qv = ws + 1392;                             // 2560
  float2* den2 = (float2*)(qv + 2 * KC * DD);        // NN float2
  float* partial = (float*)(den2 + NN);              // NBK*KC*DD
  float* cntpart = partial + (size_t)NBK * KC * DD;  // NBK*KC
  int* cnt = (int*)(cntpart + NBK * KC);             // NN*KC ints
  unsigned char* cl8 = (unsigned char*)(cnt + (size_t)NN * KC);  // NN bytes
  // total ~10.2 MB

  hipMemsetAsync(cnt, 0, (size_t)NN * KC * sizeof(int), stream);

  for (int it = 0; it < NITER; ++it) {
    const float* csrc = (it == 0) ? x : c;
    k_iter6<<<NBK, 256, 0, stream>>>(x, csrc, partial, cntpart, cl8,
                                     it == NITER - 1);
    k_update2<<<KC * 16, 256, 0, stream>>>(partial, cntpart, c);
  }
  k_qv<<<2 * KC, DD, 0, stream>>>(c, WQ, WV, qv);
  k_att<<<1, DD, 0, stream>>>(qv, CA);
  const int TOT_BLKS = (NE4 + 255) / 256;  // 3125
  const int HALF_BLKS = (TOT_BLKS + 1) / 2;
  k_cnt<<<HALF_BLKS, 256, 0, stream>>>(e0, e1, cl8, cnt, 0);
  k_cnt<<<TOT_BLKS - HALF_BLKS, 256, 0, stream>>>(e0, e1, cl8, cnt,
                                                  HALF_BLKS * 256);
  k_tab2<<<(NN + 255) / 256, 256, 0, stream>>>(cl8, cnt, CA, den2);
  const int GB = (NE4 / 2 + 255) / 256;  // 1563
  k_gather2<<<GB, 256, 0, stream>>>(e0, e1, cl8, CA, den2, out);
}